// Round 1
// baseline (315.164 us; speedup 1.0000x reference)
//
#include <hip/hip_runtime.h>

// CapsNet forward, fp32.
// Kernel 1: conv1 9x9 VALID stride1: [B,1,28,28] -> [B,16,20,20]
// Kernel 2: conv2 9x9 VALID stride2: [B,16,20,20] -> [B,32,6,6] -> u [B,144,8]
// Kernel 3: per-sample u_hat (LDS) + 3 routing iters + squash -> pred, v

__global__ __launch_bounds__(320) void conv1_kernel(
    const float* __restrict__ in, const float* __restrict__ w,
    const float* __restrict__ bias, float* __restrict__ x1) {
  __shared__ __align__(16) float sIn[784];    // 28x28
  __shared__ float sW[1296];                  // 16x81
  int b = blockIdx.x, t = threadIdx.x;
  const float* inb = in + b * 784;
  for (int i = t; i < 784; i += 320) sIn[i] = inb[i];
  for (int i = t; i < 1296; i += 320) sW[i] = w[i];
  __syncthreads();
  int co = t / 20, oh = t % 20;   // 16*20 = 320 work items, all threads active
  float bv = bias[co];
  float acc[20];
#pragma unroll
  for (int j = 0; j < 20; ++j) acc[j] = bv;
#pragma unroll
  for (int kh = 0; kh < 9; ++kh) {
    float r[28];
    const float4* row = (const float4*)&sIn[(oh + kh) * 28];
#pragma unroll
    for (int q = 0; q < 7; ++q) {
      float4 v = row[q];
      r[q * 4 + 0] = v.x; r[q * 4 + 1] = v.y; r[q * 4 + 2] = v.z; r[q * 4 + 3] = v.w;
    }
    const float* wr = &sW[co * 81 + kh * 9];
#pragma unroll
    for (int kw = 0; kw < 9; ++kw) {
      float wv = wr[kw];
#pragma unroll
      for (int j = 0; j < 20; ++j) acc[j] += wv * r[kw + j];
    }
  }
  float* outp = x1 + b * 6400 + co * 400 + oh * 20;
#pragma unroll
  for (int q = 0; q < 5; ++q) {
    *(float4*)&outp[q * 4] =
        make_float4(acc[q * 4], acc[q * 4 + 1], acc[q * 4 + 2], acc[q * 4 + 3]);
  }
}

__global__ __launch_bounds__(192) void conv2_kernel(
    const float* __restrict__ x1, const float* __restrict__ w,
    const float* __restrict__ bias, float* __restrict__ u) {
  __shared__ __align__(16) float sIn[6400];   // [16][20][20]
  int b = blockIdx.x, t = threadIdx.x;
  const float4* inb = (const float4*)(x1 + b * 6400);
  float4* s4 = (float4*)sIn;
  for (int i = t; i < 1600; i += 192) s4[i] = inb[i];
  __syncthreads();
  int co = t / 6, oh = t % 6;   // 32*6 = 192 work items
  float bv = bias[co];
  float acc[6];
#pragma unroll
  for (int j = 0; j < 6; ++j) acc[j] = bv;
  const float* wc = w + co * 1296;
  for (int ci = 0; ci < 16; ++ci) {
#pragma unroll
    for (int kh = 0; kh < 9; ++kh) {
      int ih = oh * 2 + kh;
      const float4* row = (const float4*)&sIn[ci * 400 + ih * 20];
      float r[20];
#pragma unroll
      for (int q = 0; q < 5; ++q) {
        float4 v = row[q];
        r[q * 4 + 0] = v.x; r[q * 4 + 1] = v.y; r[q * 4 + 2] = v.z; r[q * 4 + 3] = v.w;
      }
      const float* wr = wc + ci * 81 + kh * 9;
#pragma unroll
      for (int kw = 0; kw < 9; ++kw) {
        float wv = wr[kw];
#pragma unroll
        for (int ow = 0; ow < 6; ++ow) acc[ow] += wv * r[ow * 2 + kw];
      }
    }
  }
  // x[b,co,oh,ow] -> u[b, (co&3)*36 + oh*6 + ow, co>>2]
  int c8 = co >> 2;
  int ibase = (co & 3) * 36 + oh * 6;
  float* ub = u + b * 1152;
#pragma unroll
  for (int ow = 0; ow < 6; ++ow) ub[(ibase + ow) * 8 + c8] = acc[ow];
}

__global__ __launch_bounds__(512) void routing_kernel(
    const float* __restrict__ u, const float* __restrict__ W,
    float* __restrict__ out, int B) {
  __shared__ __align__(16) float uh[23040];   // u_hat [144][160]  (o*16+d)
  __shared__ __align__(16) float us[1152];    // u [144][8]
  __shared__ float blog[1440];                // b [144][10]
  __shared__ float cc[1440];                  // c [144][10]
  __shared__ __align__(16) float vv[160];     // v [10][16]
  __shared__ float ss[160];                   // s [10][16]
  int b = blockIdx.x, t = threadIdx.x;
  for (int i = t; i < 1152; i += 512) us[i] = u[b * 1152 + i];
  for (int i = t; i < 1440; i += 512) blog[i] = 0.0f;
  __syncthreads();
  // u_hat[idx] = dot8(W[idx*8 .. idx*8+7], us[i*8 .. ])  with idx = i*160 + o*16 + d
  const float4* W4 = (const float4*)W;
  for (int idx = t; idx < 23040; idx += 512) {
    int i = idx / 160;
    float4 wa = W4[idx * 2], wb = W4[idx * 2 + 1];
    const float4* up = (const float4*)&us[i * 8];
    float4 ua = up[0], ub2 = up[1];
    uh[idx] = wa.x * ua.x + wa.y * ua.y + wa.z * ua.z + wa.w * ua.w +
              wb.x * ub2.x + wb.y * ub2.y + wb.z * ub2.z + wb.w * ub2.w;
  }
  __syncthreads();

  for (int it = 0; it < 3; ++it) {
    if (it > 0) {
      // softmax over o for each input capsule i
      if (t < 144) {
        const float* br = &blog[t * 10];
        float mx = br[0];
#pragma unroll
        for (int o = 1; o < 10; ++o) mx = fmaxf(mx, br[o]);
        float e[10];
        float sum = 0.f;
#pragma unroll
        for (int o = 0; o < 10; ++o) { e[o] = __expf(br[o] - mx); sum += e[o]; }
        float inv = 1.0f / sum;
#pragma unroll
        for (int o = 0; o < 10; ++o) cc[t * 10 + o] = e[o] * inv;
      }
      __syncthreads();
    }
    // s[o][d] = sum_i c[i][o] * uh[i][o*16+d]
    if (t < 160) {
      int o = t >> 4;
      float acc = 0.f;
      if (it == 0) {
        for (int i = 0; i < 144; ++i) acc += uh[i * 160 + t];
        acc *= 0.1f;   // softmax of zeros
      } else {
        for (int i = 0; i < 144; ++i) acc += cc[i * 10 + o] * uh[i * 160 + t];
      }
      ss[t] = acc;
    }
    __syncthreads();
    // squash
    if (t < 10) {
      float sq = 0.f;
#pragma unroll
      for (int d = 0; d < 16; ++d) { float x = ss[t * 16 + d]; sq += x * x; }
      float coef = (sq / (1.0f + sq)) / sqrtf(sq + 1e-8f);
#pragma unroll
      for (int d = 0; d < 16; ++d) vv[t * 16 + d] = coef * ss[t * 16 + d];
      if (it == 2) out[b * 10 + t] = coef * sqrtf(sq);   // pred = ||v||
    }
    __syncthreads();
    // b += sum_d uh[i][o*16+d] * v[o][d]   (skip on final iter: dead)
    if (it < 2) {
      for (int idx = t; idx < 1440; idx += 512) {
        int i = idx / 10, o = idx % 10;
        const float4* uhp = (const float4*)&uh[i * 160 + o * 16];
        const float4* vp = (const float4*)&vv[o * 16];
        float dot = 0.f;
#pragma unroll
        for (int q = 0; q < 4; ++q) {
          float4 a = uhp[q], v2 = vp[q];
          dot += a.x * v2.x + a.y * v2.y + a.z * v2.z + a.w * v2.w;
        }
        blog[idx] += dot;
      }
      __syncthreads();
    }
  }
  if (t < 160) out[B * 10 + b * 160 + t] = vv[t];
}

extern "C" void kernel_launch(void* const* d_in, const int* in_sizes, int n_in,
                              void* d_out, int out_size, void* d_ws, size_t ws_size,
                              hipStream_t stream) {
  const float* in = (const float*)d_in[0];
  const float* w1 = (const float*)d_in[1];
  const float* b1 = (const float*)d_in[2];
  const float* w2 = (const float*)d_in[3];
  const float* b2 = (const float*)d_in[4];
  const float* Wr = (const float*)d_in[5];
  float* out = (float*)d_out;
  float* ws = (float*)d_ws;
  int B = in_sizes[0] / 784;

  float* x1 = ws;                       // [B][16][20][20] = B*6400 floats
  float* u  = ws + (size_t)B * 6400;    // [B][144][8]     = B*1152 floats

  conv1_kernel<<<B, 320, 0, stream>>>(in, w1, b1, x1);
  conv2_kernel<<<B, 192, 0, stream>>>(x1, w2, b2, u);
  routing_kernel<<<B, 512, 0, stream>>>(u, Wr, out, B);
}